// Round 8
// baseline (57.631 us; speedup 1.0000x reference)
//
#include <hip/hip_runtime.h>
#include <math.h>

#define DIMS 3
#define NPTS 320
#define HID  128
#define RANK 64
#define LROW 256   // LDS bytes per c row: hi 128B | lo 128B, XOR-swizzled
#define PB   4     // points per mlp block

typedef __attribute__((ext_vector_type(8)))  short bf16x8;
typedef __attribute__((ext_vector_type(16))) float f32x16;

// round-to-nearest-even float -> bf16 bits
static __device__ __forceinline__ unsigned short f2bf_rn(float x) {
    union { float f; unsigned int u; } v; v.f = x;
    unsigned int r = v.u + 0x7fffu + ((v.u >> 16) & 1u);
    return (unsigned short)(r >> 16);
}
static __device__ __forceinline__ float bf2f(unsigned short h) {
    union { unsigned int u; float f; } v; v.u = ((unsigned int)h) << 16;
    return v.f;
}

// ---------------- Phase 1: point-batched per-dim MLP ------------------------
// 240 blocks x 128 thr; each block does PB=4 points of one dim, so each
// weight line is fetched once per 4 points (L2 traffic /4).
__global__ __launch_bounds__(HID)
void mlp_kernel(const float* __restrict__ xs,
                const float* __restrict__ W0, const float* __restrict__ b0,
                const float* __restrict__ W1, const float* __restrict__ b1,
                const float* __restrict__ W2, const float* __restrict__ b2,
                const float* __restrict__ W3, const float* __restrict__ b3,
                float* __restrict__ f01t,
                unsigned short* __restrict__ f2hi,
                unsigned short* __restrict__ f2lo) {
    const int blk = blockIdx.x;
    const int d  = blk / (NPTS / PB);
    const int n0 = (blk - d * (NPTS / PB)) * PB;
    const int j  = threadIdx.x;

    __shared__ float ha[PB][HID];
    __shared__ float hb[PB][HID];

    float x[PB];
    #pragma unroll
    for (int p = 0; p < PB; ++p) x[p] = xs[d * NPTS + n0 + p];

    {
        float w = W0[d * HID + j], bb = b0[d * HID + j];
        #pragma unroll
        for (int p = 0; p < PB; ++p) ha[p][j] = tanhf(fmaf(x[p], w, bb));
    }
    __syncthreads();

    {
        float acc[PB];
        #pragma unroll
        for (int p = 0; p < PB; ++p) acc[p] = b1[d * HID + j];
        const float* w = W1 + d * HID * HID + j;
        #pragma unroll 8
        for (int k = 0; k < HID; ++k) {
            float wv = w[k * HID];
            #pragma unroll
            for (int p = 0; p < PB; ++p) acc[p] = fmaf(ha[p][k], wv, acc[p]);
        }
        #pragma unroll
        for (int p = 0; p < PB; ++p) hb[p][j] = tanhf(acc[p]);
    }
    __syncthreads();

    {
        float acc[PB];
        #pragma unroll
        for (int p = 0; p < PB; ++p) acc[p] = b2[d * HID + j];
        const float* w = W2 + d * HID * HID + j;
        #pragma unroll 8
        for (int k = 0; k < HID; ++k) {
            float wv = w[k * HID];
            #pragma unroll
            for (int p = 0; p < PB; ++p) acc[p] = fmaf(hb[p][k], wv, acc[p]);
        }
        __syncthreads();   // hb reuse barrier not needed (ha dest); protect ha read below
        #pragma unroll
        for (int p = 0; p < PB; ++p) ha[p][j] = tanhf(acc[p]);
    }
    __syncthreads();

    if (j < RANK) {
        float acc[PB];
        #pragma unroll
        for (int p = 0; p < PB; ++p) acc[p] = b3[d * RANK + j];
        const float* w = W3 + d * HID * RANK + j;
        #pragma unroll 8
        for (int k = 0; k < HID; ++k) {
            float wv = w[k * RANK];
            #pragma unroll
            for (int p = 0; p < PB; ++p) acc[p] = fmaf(ha[p][k], wv, acc[p]);
        }
        #pragma unroll
        for (int p = 0; p < PB; ++p) {
            int n = n0 + p;
            if (d == 0) {
                f01t[n * RANK + j] = acc[p];                 // f0t[a][r]
            } else if (d == 1) {
                f01t[(NPTS + n) * RANK + j] = acc[p];        // f1t[b][r]
            } else {
                unsigned short hi = f2bf_rn(acc[p]);
                f2hi[n * RANK + j] = hi;
                f2lo[n * RANK + j] = f2bf_rn(acc[p] - bf2f(hi));
            }
        }
    }
}

// ---------------- Phase 2: persistent-block CP via 32x32x16 bf16 MFMA -------
// out[a,b,c] = sum_r (f0[a,r]*f1[b,r]) * f2[c,r]
// 512 blocks (2/CU, 80 KB LDS = full f2 hi|lo swizzled). 4 waves =
// (b-subtile 32) x (c-half 160). Per tile (1 a x 64 b x 320 c): compute all
// 5 c-tiles into registers, then store ROW-MAJOR so each wave emits 640 B
// contiguous runs per output row (DRAM-page-friendly write stream).
__global__ __launch_bounds__(256, 2)
void cp_mfma_kernel(const float* __restrict__ f01t,
                    const unsigned short* __restrict__ f2hi,
                    const unsigned short* __restrict__ f2lo,
                    float* __restrict__ out) {
    const int tx = threadIdx.x;
    const int w  = tx >> 6;
    const int bsub  = (w & 1) * 32;       // b sub-tile
    const int chalf = (w >> 1) * 160;     // c half
    const int l  = tx & 63;
    const int lc = l & 31;                // A row(b) / B col(c) / D col(c)
    const int hw = l >> 5;                // half-wave -> k sub-group

    __shared__ char sB[NPTS * LROW];      // 80 KB

    // ---- stage full f2 hi/lo once (2560 float4 each, 10/thread) ----
    #pragma unroll
    for (int i = 0; i < 10; ++i) {
        int idx = tx + i * 256;           // 0..2559
        int row = idx >> 3;
        int g   = (idx & 7) << 4;
        int sw  = (row & 15) << 4;
        *(float4*)(&sB[row * LROW + (g ^ sw)])         = ((const float4*)f2hi)[idx];
        *(float4*)(&sB[row * LROW + ((128 + g) ^ sw)]) = ((const float4*)f2lo)[idx];
    }
    __syncthreads();

    for (int t = blockIdx.x; t < NPTS * 5; t += 512) {
        const int a  = t / 5;
        const int bb = (t - a * 5) * 64 + bsub;

        const float* f0p = f01t + (size_t)a * RANK + hw * 8;
        const float* f1p = f01t + (size_t)(NPTS + bb + lc) * RANK + hw * 8;

        // ---- A fragments: g[j] = f0[a][k]*f1[b][k], k = ks*16 + hw*8 + j ----
        bf16x8 ahi[4], alo[4];
        #pragma unroll
        for (int ks = 0; ks < 4; ++ks) {
            const int k0 = ks * 16;
            float4 f0a = *(const float4*)(f0p + k0);
            float4 f0b = *(const float4*)(f0p + k0 + 4);
            float4 f1a = *(const float4*)(f1p + k0);
            float4 f1b = *(const float4*)(f1p + k0 + 4);

            float g[8];
            g[0] = f1a.x * f0a.x; g[1] = f1a.y * f0a.y;
            g[2] = f1a.z * f0a.z; g[3] = f1a.w * f0a.w;
            g[4] = f1b.x * f0b.x; g[5] = f1b.y * f0b.y;
            g[6] = f1b.z * f0b.z; g[7] = f1b.w * f0b.w;

            #pragma unroll
            for (int j = 0; j < 8; ++j) {
                unsigned short hi = f2bf_rn(g[j]);
                ahi[ks][j] = (short)hi;
                alo[ks][j] = (short)f2bf_rn(g[j] - bf2f(hi));
            }
        }

        // ---- compute all 5 c-tiles into registers ----
        f32x16 acc[5];
        #pragma unroll
        for (int ct = 0; ct < 5; ++ct) {
            const int lr = chalf + ct * 32 + lc;
            const int sw2 = (lr & 15) << 4;
            const char* rowp = &sB[lr * LROW];

            #pragma unroll
            for (int jj = 0; jj < 16; ++jj) acc[ct][jj] = 0.0f;

            #pragma unroll
            for (int ks = 0; ks < 4; ++ks) {
                const int base = ks * 32 + (hw << 4);
                bf16x8 b_hi = *(const bf16x8*)(rowp + (base ^ sw2));
                bf16x8 b_lo = *(const bf16x8*)(rowp + ((128 + base) ^ sw2));
                acc[ct] = __builtin_amdgcn_mfma_f32_32x32x16_bf16(ahi[ks], b_hi, acc[ct], 0, 0, 0);
                acc[ct] = __builtin_amdgcn_mfma_f32_32x32x16_bf16(ahi[ks], b_lo, acc[ct], 0, 0, 0);
                acc[ct] = __builtin_amdgcn_mfma_f32_32x32x16_bf16(alo[ks], b_hi, acc[ct], 0, 0, 0);
            }
        }

        // ---- stores: row-major => 640 B contiguous runs per row ----
        // D: col(c)=lc, row(b) = (q&3) + 8*(q>>2) + 4*hw
        float* obase = out + ((size_t)a * NPTS + bb) * NPTS + chalf + lc;
        #pragma unroll
        for (int q = 0; q < 16; ++q) {
            const int row = (q & 3) + 8 * (q >> 2) + 4 * hw;
            float* orow = obase + (size_t)row * NPTS;
            #pragma unroll
            for (int ct = 0; ct < 5; ++ct) {
                orow[ct * 32] = acc[ct][q];
            }
        }
    }
}

extern "C" void kernel_launch(void* const* d_in, const int* in_sizes, int n_in,
                              void* d_out, int out_size, void* d_ws, size_t ws_size,
                              hipStream_t stream) {
    const float* xs = (const float*)d_in[0];
    const float* W0 = (const float*)d_in[1];
    const float* b0 = (const float*)d_in[2];
    const float* W1 = (const float*)d_in[3];
    const float* b1 = (const float*)d_in[4];
    const float* W2 = (const float*)d_in[5];
    const float* b2 = (const float*)d_in[6];
    const float* W3 = (const float*)d_in[7];
    const float* b3 = (const float*)d_in[8];

    // workspace: f01t float[2][NPTS][RANK] | f2hi ushort[NPTS][RANK] | f2lo same
    float* f01t = (float*)d_ws;
    unsigned short* f2hi = (unsigned short*)((char*)d_ws + 2 * NPTS * RANK * 4);
    unsigned short* f2lo = f2hi + NPTS * RANK;
    float* out = (float*)d_out;

    mlp_kernel<<<dim3(DIMS * NPTS / PB), dim3(HID), 0, stream>>>(
        xs, W0, b0, W1, b1, W2, b2, W3, b3, f01t, f2hi, f2lo);

    cp_mfma_kernel<<<dim3(512), dim3(256), 0, stream>>>(f01t, f2hi, f2lo, out);
}

// Round 9
// 40.634 us; speedup vs baseline: 1.4183x; 1.4183x over previous
//
#include <hip/hip_runtime.h>
#include <math.h>

#define DIMS 3
#define NPTS 320
#define HID  128
#define RANK 64
#define CH   160   // c rows per block (half of NPTS)
#define LROW 128   // LDS bytes per c row (single bf16 table), XOR-swizzled

typedef __attribute__((ext_vector_type(8)))  short bf16x8;
typedef __attribute__((ext_vector_type(16))) float f32x16;

// round-to-nearest-even float -> bf16 bits
static __device__ __forceinline__ unsigned short f2bf_rn(float x) {
    union { float f; unsigned int u; } v; v.f = x;
    unsigned int r = v.u + 0x7fffu + ((v.u >> 16) & 1u);
    return (unsigned short)(r >> 16);
}
static __device__ __forceinline__ float bf2f(unsigned short h) {
    union { unsigned int u; float f; } v; v.u = ((unsigned int)h) << 16;
    return v.f;
}

// ---------------- Phase 1: per-dim MLP -> transposed factor tables ----------
// f0t[a][r], f1t[b][r] fp32; f2 rounded once to bf16 (f2hi[c][r]).
__global__ __launch_bounds__(HID)
void mlp_kernel(const float* __restrict__ xs,
                const float* __restrict__ W0, const float* __restrict__ b0,
                const float* __restrict__ W1, const float* __restrict__ b1,
                const float* __restrict__ W2, const float* __restrict__ b2,
                const float* __restrict__ W3, const float* __restrict__ b3,
                float* __restrict__ f01t,
                unsigned short* __restrict__ f2hi) {
    int blk = blockIdx.x;
    int d = blk / NPTS, n = blk % NPTS;
    int j = threadIdx.x;

    __shared__ float ha[HID];
    __shared__ float hb[HID];

    float x = xs[d * NPTS + n];

    ha[j] = tanhf(fmaf(x, W0[d * HID + j], b0[d * HID + j]));
    __syncthreads();

    {
        float acc = b1[d * HID + j];
        const float* w = W1 + d * HID * HID + j;
        #pragma unroll 16
        for (int k = 0; k < HID; ++k) acc = fmaf(ha[k], w[k * HID], acc);
        hb[j] = tanhf(acc);
    }
    __syncthreads();

    {
        float acc = b2[d * HID + j];
        const float* w = W2 + d * HID * HID + j;
        #pragma unroll 16
        for (int k = 0; k < HID; ++k) acc = fmaf(hb[k], w[k * HID], acc);
        ha[j] = tanhf(acc);
    }
    __syncthreads();

    if (j < RANK) {
        float acc = b3[d * RANK + j];
        const float* w = W3 + d * HID * RANK + j;
        #pragma unroll 16
        for (int k = 0; k < HID; ++k) acc = fmaf(ha[k], w[k * RANK], acc);

        if (d == 0) {
            f01t[n * RANK + j] = acc;                    // f0t[a][r]
        } else if (d == 1) {
            f01t[(NPTS + n) * RANK + j] = acc;           // f1t[b][r]
        } else {
            f2hi[n * RANK + j] = f2bf_rn(acc);           // single-rounded B
        }
    }
}

// ---------------- Phase 2: persistent-block CP via 32x32x16 bf16 MFMA -------
// out[a,b,c] = sum_r (f0[a,r]*f1[b,r]) * f2[c,r]
// R6 structure (proven best): 1024 blocks x 128 thr (2 waves), block owns a
// c-half staged once in LDS (now 20 KB, bf16 single), waves split b-subtiles.
// Per ct: 4 swizzled ds_read_b128 + 8 MFMAs (A hi/lo x B) + 16 interleaved
// full-line stores. A built in-register with hi/lo split (precision keeper).
__global__ __launch_bounds__(128, 2)
void cp_mfma_kernel(const float* __restrict__ f01t,
                    const unsigned short* __restrict__ f2hi,
                    float* __restrict__ out) {
    const int tx = threadIdx.x;
    const int w  = tx >> 6;        // wave -> b sub-tile
    const int l  = tx & 63;
    const int lc = l & 31;         // A row(b) / B col(c) / D col(c)
    const int hw = l >> 5;         // half-wave -> k sub-group

    const int c0 = (blockIdx.x & 1) * CH;

    __shared__ char sB[CH * LROW];   // 20 KB

    // ---- stage c-half of f2 once (1280 float4, 10/thread), swizzled ----
    #pragma unroll
    for (int i = 0; i < 10; ++i) {
        int idx = tx + i * 128;               // 0..1279
        int row = idx >> 3;                   // local c row
        int g   = (idx & 7) << 4;             // 16B slot within 128B row
        *(float4*)(&sB[row * LROW + (g ^ ((row & 7) << 4))]) =
            ((const float4*)f2hi)[c0 * 8 + idx];
    }
    __syncthreads();

    for (int t = blockIdx.x >> 1; t < NPTS * 5; t += 512) {
        const int a   = t / 5;
        const int b0w = (t - a * 5) * 64 + w * 32;
        const float* f0p = f01t + (size_t)a * RANK + hw * 8;
        const float* f1p = f01t + (size_t)(NPTS + b0w + lc) * RANK + hw * 8;

        // ---- A fragments: g[j] = f0[a][k]*f1[b][k], k = ks*16 + hw*8 + j ----
        bf16x8 ahi[4], alo[4];
        #pragma unroll
        for (int ks = 0; ks < 4; ++ks) {
            const int k0 = ks * 16;
            float4 f0a = *(const float4*)(f0p + k0);
            float4 f0b = *(const float4*)(f0p + k0 + 4);
            float4 f1a = *(const float4*)(f1p + k0);
            float4 f1b = *(const float4*)(f1p + k0 + 4);

            float g[8];
            g[0] = f1a.x * f0a.x; g[1] = f1a.y * f0a.y;
            g[2] = f1a.z * f0a.z; g[3] = f1a.w * f0a.w;
            g[4] = f1b.x * f0b.x; g[5] = f1b.y * f0b.y;
            g[6] = f1b.z * f0b.z; g[7] = f1b.w * f0b.w;

            #pragma unroll
            for (int j = 0; j < 8; ++j) {
                unsigned short hi = f2bf_rn(g[j]);
                ahi[ks][j] = (short)hi;
                alo[ks][j] = (short)f2bf_rn(g[j] - bf2f(hi));
            }
        }

        // ---- 5 c-tiles of 32: 4 LDS reads + 8 MFMAs + 16 stores each ----
        #pragma unroll
        for (int ct = 0; ct < 5; ++ct) {
            const int lr = c0 % CH + ct * 32 + lc;    // local c row (0..159)
            const int sw = (lr & 7) << 4;
            const char* rowp = &sB[(ct * 32 + lc) * LROW];

            f32x16 acc;
            #pragma unroll
            for (int jj = 0; jj < 16; ++jj) acc[jj] = 0.0f;

            #pragma unroll
            for (int ks = 0; ks < 4; ++ks) {
                const int base = ks * 32 + (hw << 4);       // k slot bytes
                bf16x8 b = *(const bf16x8*)(rowp + (base ^ (((ct * 32 + lc) & 7) << 4)));
                acc = __builtin_amdgcn_mfma_f32_32x32x16_bf16(ahi[ks], b, acc, 0, 0, 0);
                acc = __builtin_amdgcn_mfma_f32_32x32x16_bf16(alo[ks], b, acc, 0, 0, 0);
            }

            // D: col(c)=lc, row(b) = (q&3) + 8*(q>>2) + 4*hw
            float* obase = out + ((size_t)a * NPTS + b0w) * NPTS + c0 + ct * 32 + lc;
            #pragma unroll
            for (int q = 0; q < 16; ++q) {
                int row = (q & 3) + 8 * (q >> 2) + 4 * hw;
                obase[(size_t)row * NPTS] = acc[q];
            }
        }
    }
}

extern "C" void kernel_launch(void* const* d_in, const int* in_sizes, int n_in,
                              void* d_out, int out_size, void* d_ws, size_t ws_size,
                              hipStream_t stream) {
    const float* xs = (const float*)d_in[0];
    const float* W0 = (const float*)d_in[1];
    const float* b0 = (const float*)d_in[2];
    const float* W1 = (const float*)d_in[3];
    const float* b1 = (const float*)d_in[4];
    const float* W2 = (const float*)d_in[5];
    const float* b2 = (const float*)d_in[6];
    const float* W3 = (const float*)d_in[7];
    const float* b3 = (const float*)d_in[8];

    // workspace: f01t float[2][NPTS][RANK] | f2hi ushort[NPTS][RANK]
    float* f01t = (float*)d_ws;
    unsigned short* f2hi = (unsigned short*)((char*)d_ws + 2 * NPTS * RANK * 4);
    float* out = (float*)d_out;

    mlp_kernel<<<dim3(DIMS * NPTS), dim3(HID), 0, stream>>>(
        xs, W0, b0, W1, b1, W2, b2, W3, b3, f01t, f2hi);

    cp_mfma_kernel<<<dim3(1024), dim3(128), 0, stream>>>(f01t, f2hi, out);
}